// Round 13
// baseline (323.304 us; speedup 1.0000x reference)
//
#include <hip/hip_runtime.h>
#include <hip/hip_bf16.h>
#include <hip/hip_fp16.h>

// Problem constants
#define BATCH 64
#define C_IN 16
#define T0 8192
#define T1 4096   // after pool1
#define T2 2048   // after pool2 (nodes per batch)
#define N_NODES (BATCH * T2)   // 131072
#define HID 64
#define NOUT 10

// Coarse-bucket edge partition parameters
#define NCB 256
#define CB_SHIFT 9
#define CB_TGT 512
#define RCAP 9216
#define PC_EDGES 2048
#define PC_CAP 28

// packed edge record: bits[0:17) = source r, bits[17:26) = local col
#define PK_RMASK 0x1FFFF

// per-block staged edge-span capacity
#define EC 1024

// zero-row index (tables have N_NODES+1 rows; row N_NODES is all zeros)
#define ZROW N_NODES

// transposed conv-input LDS tile: row = position, 16 ci halves + pad.
// ROWW=24 halves (48B = 12 words): b128 reads at pos*12 words tile all 32
// banks (stride-12 start-bank cycle {0,12,24,4,16,28,8,20} -> 2-way = free).
#define ROWW 24

// fp8 gather tables: rows scaled by S on store, /S folded into dis at agg.
#define FP8_SCALE 256.0f
#define FP8_SINV  (1.0f / 256.0f)

typedef __fp16 half8 __attribute__((ext_vector_type(8)));
typedef __fp16 half4v __attribute__((ext_vector_type(4)));
typedef float floatx4 __attribute__((ext_vector_type(4)));
typedef float floatx2 __attribute__((ext_vector_type(2)));

// ---------------- FUSED conv1 + partition (r9/r12 structure; conv1's 46us
// is invariant across 5 internal variants — parked). NEW: partition path
// also accumulates global node degrees (fire-and-forget atomics) so the
// next kernel can compute dis itself, breaking the build_csr -> conv2
// serial dependency.
__global__ __launch_bounds__(256) void conv1_partition(
    const float* __restrict__ x, const float* __restrict__ w,
    const float* __restrict__ bias, __fp16* __restrict__ h1,
    const int* __restrict__ ei, int E,
    int* __restrict__ rcnt, int* __restrict__ gpairs,
    int* __restrict__ deg_g,
    float* __restrict__ pool, unsigned char* __restrict__ xw,
    unsigned char* __restrict__ xw2) {
  __shared__ int smem_i[NCB + NCB * PC_CAP];   // 29,696 B union
  if ((blockIdx.x & 1) == 0) {
    // ======== conv1 path (MFMA im2col GEMM, K=80 pad 96, N=16co)
    __fp16* xs = (__fp16*)smem_i;              // 528*24*2 = 25,344 B
    int bid = blockIdx.x >> 1;
    int b = bid >> 4;
    int tp0 = (bid & 15) * 256;
    if (bid == 0) {
      for (int k = threadIdx.x; k < BATCH * HID; k += 256) pool[k] = 0.f;
      if (threadIdx.x < 16) {
        ((unsigned*)(xw + (size_t)ZROW * 64))[threadIdx.x] = 0u;
        ((unsigned*)(xw2 + (size_t)ZROW * 64))[threadIdx.x] = 0u;
      }
    }
    int t_base = 2 * tp0 - 8;
    const float* xb = x + (size_t)b * C_IN * T0;
    {
      int ci = threadIdx.x >> 4;
      int l16 = threadIdx.x & 15;
      const float* xrow = xb + ci * T0;
      float4 va[4];
#pragma unroll
      for (int k = 0; k < 4; ++k) {
        int c4 = l16 + k * 16;
        int gt = t_base + c4 * 4;
        va[k] = make_float4(0.f, 0.f, 0.f, 0.f);
        if (gt >= 0 && gt + 4 <= T0) va[k] = *(const float4*)(xrow + gt);
      }
#pragma unroll
      for (int k = 0; k < 4; ++k) {
        int c4 = l16 + k * 16;
        __fp16* d = xs + (c4 * 4) * ROWW + ci;
        d[0] = (__fp16)va[k].x;
        d[ROWW] = (__fp16)va[k].y;
        d[2 * ROWW] = (__fp16)va[k].z;
        d[3 * ROWW] = (__fp16)va[k].w;
      }
      float4 vb[5];
      int okb[5];
#pragma unroll
      for (int k = 0; k < 5; ++k) {
        int c4 = l16 + (4 + k) * 16;
        okb[k] = (c4 < 132);
        int gt = t_base + c4 * 4;
        vb[k] = make_float4(0.f, 0.f, 0.f, 0.f);
        if (okb[k] && gt >= 0 && gt + 4 <= T0) vb[k] = *(const float4*)(xrow + gt);
      }
#pragma unroll
      for (int k = 0; k < 5; ++k) {
        if (okb[k]) {
          int c4 = l16 + (4 + k) * 16;
          __fp16* d = xs + (c4 * 4) * ROWW + ci;
          d[0] = (__fp16)vb[k].x;
          d[ROWW] = (__fp16)vb[k].y;
          d[2 * ROWW] = (__fp16)vb[k].z;
          d[3 * ROWW] = (__fp16)vb[k].w;
        }
      }
    }
    int ln = threadIdx.x & 15;
    int q = (threadIdx.x & 63) >> 4;
    int wib = threadIdx.x >> 6;
    half8 wb[3];
#pragma unroll
    for (int ks = 0; ks < 3; ++ks) {
      int kk = ks * 2 + (q >> 1);
#pragma unroll
      for (int j = 0; j < 8; ++j) {
        int ci = (q & 1) * 8 + j;
        float wv = (kk < 5) ? w[(ln * 16 + ci) * 5 + kk] : 0.f;
        wb[ks][j] = (__fp16)wv;
      }
    }
    float bv = bias[ln];
    __syncthreads();
    int qh = q >> 1, qo = (q & 1) * 8;
#pragma unroll 2
    for (int mtl = 0; mtl < 8; ++mtl) {
      int mt = wib * 8 + mtl;
      int posb = mt * 16 + ln + qh + 6;
      half8 a0 = *(const half8*)(xs + posb * ROWW + qo);
      half8 a1 = *(const half8*)(xs + (posb + 2) * ROWW + qo);
      half8 a2 = *(const half8*)(xs + (posb + 4) * ROWW + qo);
      floatx4 c0 = {0.f, 0.f, 0.f, 0.f};
      c0 = __builtin_amdgcn_mfma_f32_16x16x32_f16(a0, wb[0], c0, 0, 0, 0);
      c0 = __builtin_amdgcn_mfma_f32_16x16x32_f16(a1, wb[1], c0, 0, 0, 0);
      c0 = __builtin_amdgcn_mfma_f32_16x16x32_f16(a2, wb[2], c0, 0, 0, 0);
      int tp = tp0 + mtl * 8 + q * 2 + wib * 64;
      // NOTE: tp decomposition identical to mt*8+q*2 (mt = wib*8+mtl)
      tp = tp0 + mt * 8 + q * 2;
      size_t o = ((size_t)b * T1 + tp) * 16 + ln;
      h1[o] = (__fp16)fmaxf(fmaxf(c0[0], c0[1]) + bv, 0.f);
      h1[o + 16] = (__fp16)fmaxf(fmaxf(c0[2], c0[3]) + bv, 0.f);
    }
  } else {
    // ======== partition path: preload 8 edges (one wait), then 8
    // independent atomic-slot chains + global degree accumulation.
    int* lcnt = smem_i;
    int* lpk = smem_i + NCB;
    int pid = blockIdx.x >> 1;
    if (threadIdx.x < NCB) lcnt[threadIdx.x] = 0;
    __syncthreads();
    int e0 = pid * PC_EDGES;
    int rr[8], cc[8];
#pragma unroll
    for (int j = 0; j < 8; ++j) {
      int e = e0 + j * 256 + threadIdx.x;
      rr[j] = (e < E) ? ei[e] : 0;
      cc[j] = (e < E) ? ei[E + e] : -1;
    }
#pragma unroll
    for (int j = 0; j < 8; ++j) {
      if (cc[j] >= 0) {
        atomicAdd(&deg_g[cc[j]], 1);   // fire-and-forget, no return use
        int cb = cc[j] >> CB_SHIFT;
        int pk = rr[j] | ((cc[j] & (CB_TGT - 1)) << 17);
        int slot = atomicAdd(&lcnt[cb], 1);
        if (slot < PC_CAP) {
          lpk[cb * PC_CAP + slot] = pk;
        } else {
          int pos = atomicAdd(&rcnt[cb], 1);
          if (pos < RCAP) gpairs[(size_t)cb * RCAP + pos] = pk;
        }
      }
    }
    __syncthreads();
    int t = threadIdx.x;
    if (t < NCB) {
      int n = lcnt[t];
      if (n > PC_CAP) n = PC_CAP;
      if (n > 0) {
        int base = atomicAdd(&rcnt[t], n);
        int* dst = gpairs + (size_t)t * RCAP;
        for (int k = 0; k < n; ++k) {
          int p = base + k;
          if (p < RCAP) dst[p] = lpk[t * PC_CAP + k];
        }
      }
    }
  }
}

// ---------------- FUSED build_csr + conv2_gemm1.
// bid%3==0 -> csr path (b = bid/3, 512 threads); else conv2 path
// (cid = bid - bid/3 - 1, 8 waves per 512-thread block, half per-thread
// work vs the old 256-thread version; same layouts and wave-owns-rows
// invariant). conv2 computes its own dis from deg_g (identical arithmetic
// rsqrtf(deg+1)) so it no longer waits on build_csr. LDS union 46.5 KB
// -> 3 blocks/CU = 24 waves (old conv2_gemm1: 12 waves/CU).
__global__ __launch_bounds__(512) void csr_conv2(const int* __restrict__ gpairs,
    const int* __restrict__ rcnt, int* __restrict__ ebuf,
    int* __restrict__ estart, int* __restrict__ ecnt, float* __restrict__ dis,
    const __fp16* __restrict__ h1, const float* __restrict__ w,
    const float* __restrict__ bias, const float* __restrict__ W1,
    const int* __restrict__ deg_g, unsigned char* __restrict__ xw) {
  __shared__ int smem_i[11616];   // 46,464 B union
  int bid = blockIdx.x;
  if (bid % 3 == 0) {
    // ======== build_csr path (exact r12 logic, 512 threads)
    int* deg = smem_i;
    int* cur = smem_i + 512;
    int* sc = smem_i + 1024;
    int* wsum = smem_i + 1536;
    int b = bid / 3;
    int t = threadIdx.x;
    deg[t] = 0;
    cur[t] = 0;
    __syncthreads();
    int m = rcnt[b];
    if (m > RCAP) m = RCAP;
    const int* reg = gpairs + (size_t)b * RCAP;
    for (int k0 = 0; k0 < m; k0 += 2048) {
      int p[4], have[4];
#pragma unroll
      for (int u = 0; u < 4; ++u) {
        int k = k0 + u * 512 + t;
        have[u] = (k < m);
        p[u] = have[u] ? reg[k] : 0;
      }
#pragma unroll
      for (int u = 0; u < 4; ++u)
        if (have[u]) atomicAdd(&deg[(p[u] >> 17) & (CB_TGT - 1)], 1);
    }
    __syncthreads();
    int d = deg[t];
    int lane = t & 63;
    int wv = t >> 6;
    int sum = d;
#pragma unroll
    for (int off = 1; off < 64; off <<= 1) {
      int v = __shfl_up(sum, off, 64);
      if (lane >= off) sum += v;
    }
    if (lane == 63) wsum[wv] = sum;
    __syncthreads();
    int prefix = 0;
#pragma unroll
    for (int i = 0; i < 8; ++i) prefix += (i < wv) ? wsum[i] : 0;
    int excl = prefix + sum - d;
    int gi = (b << CB_SHIFT) + t;
    int base = b * RCAP;
    estart[gi] = base + excl;
    ecnt[gi] = d;
    dis[gi] = rsqrtf((float)d + 1.0f);
    sc[t] = excl;
    __syncthreads();
    for (int k0 = 0; k0 < m; k0 += 2048) {
      int p[4], have[4];
#pragma unroll
      for (int u = 0; u < 4; ++u) {
        int k = k0 + u * 512 + t;
        have[u] = (k < m);
        p[u] = have[u] ? reg[k] : 0;
      }
#pragma unroll
      for (int u = 0; u < 4; ++u) {
        if (have[u]) {
          int lc = (p[u] >> 17) & (CB_TGT - 1);
          int off = atomicAdd(&cur[lc], 1);
          ebuf[base + sc[lc] + off] = p[u] & PK_RMASK;
        }
      }
    }
  } else {
    // ======== conv2+gemm1 path (8 waves; tile = 256 pooled positions)
    __fp16* xs = (__fp16*)smem_i;               // 520*24*2 = 24,960 B
    __fp16* fs = (__fp16*)(smem_i + 6240);      // 256*40*2 = 20,480 B
    float* disl = (float*)(smem_i + 11360);     // 256*4 = 1,024 B
    int cid = bid - bid / 3 - 1;                // 0..511
    int b = cid >> 3;
    int tp0 = (cid & 7) * 256;
    int t = threadIdx.x;
    int t_base = 2 * tp0 - 2;
    int gnode0 = b * T2 + tp0;
    // dis for this tile from global degrees (scaled by FP8_SCALE)
    if (t < 256) disl[t] = rsqrtf((float)deg_g[gnode0 + t] + 1.0f) * FP8_SCALE;
    // batched register staging: 1040 chunks = 2*512 + 16; 3 preloads, 1 wait
    {
      half8 v[3];
      int row_[3], hf_[3], ok_[3];
#pragma unroll
      for (int k = 0; k < 3; ++k) {
        int idx = t + k * 512;
        ok_[k] = (idx < 520 * 2);
        int row = idx >> 1, hf = idx & 1;
        int gt = t_base + row;
        half8 z;
#pragma unroll
        for (int j = 0; j < 8; ++j) z[j] = (__fp16)0.f;
        v[k] = z;
        if (ok_[k] && gt >= 0 && gt < T1)
          v[k] = *(const half8*)(h1 + ((size_t)b * T1 + gt) * 16 + hf * 8);
        row_[k] = row; hf_[k] = hf;
      }
#pragma unroll
      for (int k = 0; k < 3; ++k)
        if (ok_[k]) *(half8*)(xs + row_[k] * ROWW + hf_[k] * 8) = v[k];
    }
    int ln = t & 15;
    int q = (t & 63) >> 4;
    int wib = t >> 6;                            // 0..7
    half8 wb[2][3];
#pragma unroll
    for (int nt = 0; nt < 2; ++nt)
#pragma unroll
      for (int ks = 0; ks < 3; ++ks) {
        int kk = ks * 2 + (q >> 1);
#pragma unroll
        for (int j = 0; j < 8; ++j) {
          int ci = (q & 1) * 8 + j;
          float wv = (kk < 5) ? w[((nt * 16 + ln) * 16 + ci) * 5 + kk] : 0.f;
          wb[nt][ks][j] = (__fp16)wv;
        }
      }
    float b20 = bias[ln];
    float b21 = bias[16 + ln];
    __syncthreads();
    int qh = q >> 1, qo = (q & 1) * 8;
#pragma unroll
    for (int mtl = 0; mtl < 4; ++mtl) {
      int mt = wib * 4 + mtl;                    // 0..31
      int posb = mt * 16 + ln + qh;
      half8 a0 = *(const half8*)(xs + posb * ROWW + qo);
      half8 a1 = *(const half8*)(xs + (posb + 2) * ROWW + qo);
      half8 a2 = *(const half8*)(xs + (posb + 4) * ROWW + qo);
      floatx4 c0 = {0.f, 0.f, 0.f, 0.f};
      floatx4 c1 = {0.f, 0.f, 0.f, 0.f};
      c0 = __builtin_amdgcn_mfma_f32_16x16x32_f16(a0, wb[0][0], c0, 0, 0, 0);
      c0 = __builtin_amdgcn_mfma_f32_16x16x32_f16(a1, wb[0][1], c0, 0, 0, 0);
      c0 = __builtin_amdgcn_mfma_f32_16x16x32_f16(a2, wb[0][2], c0, 0, 0, 0);
      c1 = __builtin_amdgcn_mfma_f32_16x16x32_f16(a0, wb[1][0], c1, 0, 0, 0);
      c1 = __builtin_amdgcn_mfma_f32_16x16x32_f16(a1, wb[1][1], c1, 0, 0, 0);
      c1 = __builtin_amdgcn_mfma_f32_16x16x32_f16(a2, wb[1][2], c1, 0, 0, 0);
      int node = mt * 8 + q * 2;                 // wave owns nodes wib*32..+31
      fs[node * 40 + ln] = (__fp16)fmaxf(fmaxf(c0[0], c0[1]) + b20, 0.f);
      fs[(node + 1) * 40 + ln] = (__fp16)fmaxf(fmaxf(c0[2], c0[3]) + b20, 0.f);
      fs[node * 40 + 16 + ln] = (__fp16)fmaxf(fmaxf(c1[0], c1[1]) + b21, 0.f);
      fs[(node + 1) * 40 + 16 + ln] = (__fp16)fmaxf(fmaxf(c1[2], c1[3]) + b21, 0.f);
    }
    // gemm1 epilogue: wave reads only its own fs rows -> no barrier needed.
    // Column-permuted W1: call tc gives lane ln output column ln*4 + tc.
    half8 bf[4];
#pragma unroll
    for (int tc = 0; tc < 4; ++tc)
#pragma unroll
      for (int j = 0; j < 8; ++j)
        bf[tc][j] = (__fp16)W1[(q * 8 + j) * 64 + ln * 4 + tc];
#pragma unroll
    for (int tt = 0; tt < 2; ++tt) {
      int lbase = (wib * 2 + tt) * 16;
      half8 a = *(const half8*)(fs + (lbase + ln) * 40 + q * 8);
      float d[4];
#pragma unroll
      for (int r = 0; r < 4; ++r) d[r] = disl[lbase + q * 4 + r];
      floatx4 acc[4];
#pragma unroll
      for (int tc = 0; tc < 4; ++tc) {
        floatx4 z = {0.f, 0.f, 0.f, 0.f};
        acc[tc] = __builtin_amdgcn_mfma_f32_16x16x32_f16(a, bf[tc], z, 0, 0, 0);
      }
#pragma unroll
      for (int r = 0; r < 4; ++r) {
        int u = __builtin_amdgcn_cvt_pk_fp8_f32(acc[0][r] * d[r], acc[1][r] * d[r], 0, 0);
        u = __builtin_amdgcn_cvt_pk_fp8_f32(acc[2][r] * d[r], acc[3][r] * d[r], u, 1);
        *(unsigned*)(xw + (size_t)(gnode0 + lbase + q * 4 + r) * 64 + ln * 4) = (unsigned)u;
      }
    }
  }
}

// ======== gather (fp8 rows, 64 B = 1 cache line), PING-PONG double-buffered
// 16-edge windows (r6 structure — best verified). es = lane>>4, ch = lane&15.
#define LOADW(dst_, b0_)                                                        \
  _Pragma("unroll")                                                             \
  for (int j = 0; j < 4; ++j) {                                                 \
    unsigned r = (unsigned)sidx[(b0_) + j * 4];                                 \
    dst_[j] = *(const unsigned*)(tab + ((r << 6) + ch4));                       \
  }
#define LOADWT(dst_, stl_, s0_, c_)                                             \
  _Pragma("unroll")                                                             \
  for (int j = 0; j < 4; ++j) {                                                 \
    int k = (s0_) + j * 4 + es;                                                 \
    unsigned r = (unsigned)sidx[(stl_) + k];                                    \
    unsigned off = (k < (c_)) ? ((r << 6) + ch4) : zoff;                        \
    dst_[j] = *(const unsigned*)(tab + off);                                    \
  }
#define CONSW(src_, ALO, AHI)                                                   \
  _Pragma("unroll")                                                             \
  for (int j = 0; j < 4; ++j) {                                                 \
    ALO += __builtin_amdgcn_cvt_pk_f32_fp8(src_[j], 0);                         \
    AHI += __builtin_amdgcn_cvt_pk_f32_fp8(src_[j], 1);                         \
  }
#define GATHER_NODE(c_, stl_, ALO, AHI)                                         \
  {                                                                             \
    int sb_ = (stl_) + es;                                                      \
    int nt_ = ((c_) + 15) >> 4;                                                 \
    int nf_ = (c_) >> 4;                                                        \
    unsigned wa_[4], wb_[4];                                                    \
    if (nt_ > 0) {                                                              \
      if (nf_ > 0) { LOADW(wa_, sb_) } else { LOADWT(wa_, stl_, 0, c_) }        \
    }                                                                           \
    for (int w_ = 0; w_ < nt_; ++w_) {                                          \
      int n_ = w_ + 1;                                                          \
      if (n_ < nt_) {                                                           \
        if (w_ & 1) {                                                           \
          if (n_ < nf_) { LOADW(wa_, sb_ + (n_ << 4)) }                         \
          else { LOADWT(wa_, stl_, n_ << 4, c_) }                               \
        } else {                                                                \
          if (n_ < nf_) { LOADW(wb_, sb_ + (n_ << 4)) }                         \
          else { LOADWT(wb_, stl_, n_ << 4, c_) }                               \
        }                                                                       \
      }                                                                         \
      if (w_ & 1) { CONSW(wb_, ALO, AHI) } else { CONSW(wa_, ALO, AHI) }        \
    }                                                                           \
  }

// ======== batched sidx staging: EC = 1024 = 4*256 -> 4 preloads, 1 wait
#define STAGE_SIDX()                                                            \
  {                                                                             \
    int v0 = 0, v1 = 0, v2 = 0, v3 = 0;                                         \
    if (t < total) v0 = ebuf[span0 + t];                                        \
    if (t + 256 < total) v1 = ebuf[span0 + t + 256];                            \
    if (t + 512 < total) v2 = ebuf[span0 + t + 512];                            \
    if (t + 768 < total) v3 = ebuf[span0 + t + 768];                            \
    if (t < total) sidx[t] = v0;                                                \
    if (t + 256 < total) sidx[t + 256] = v1;                                    \
    if (t + 512 < total) sidx[t + 512] = v2;                                    \
    if (t + 768 < total) sidx[t + 768] = v3;                                    \
  }

// ---------------- agg1 + gemm2 fused (fp8 table, staged edge span)
__global__ __launch_bounds__(256) void agg1_gemm2(const unsigned char* __restrict__ tab,
    const int* __restrict__ ebuf, const int* __restrict__ estart,
    const int* __restrict__ ecnt, const float* __restrict__ dis,
    const float* __restrict__ bias, const float* __restrict__ W2,
    unsigned char* __restrict__ xw2, int N) {
  __shared__ __fp16 g1s[16 * 72];
  __shared__ int sidx[EC + 16];   // +16: tail window may over-read in-bounds
  __shared__ int sst[16], scn[16];
  int t = threadIdx.x;
  int base16 = blockIdx.x * 16;
  if (t < 16) {
    sst[t] = estart[base16 + t];
    scn[t] = ecnt[base16 + t];
  }
  __syncthreads();
  int span0 = sst[0];
  int total = sst[15] + scn[15] - span0;
  if (total > EC) total = EC;
  STAGE_SIDX()
  __syncthreads();
  int lane = t & 63;
  int es = lane >> 4;
  int ch = lane & 15;
  int wib = t >> 6;
  unsigned ch4 = (unsigned)ch * 4u;
  unsigned zoff = ((unsigned)ZROW << 6) + ch4;
  float4 bv = *(const float4*)(bias + ch * 4);
  // gemm2 W2 fragments hoisted BEFORE the gather (r8: −10% on this kernel)
  half8 b0, b1;
#pragma unroll
  for (int j = 0; j < 8; ++j) {
    b0[j] = (__fp16)W2[((lane >> 4) * 8 + j) * 64 + wib * 16 + (lane & 15)];
    b1[j] = (__fp16)W2[(32 + (lane >> 4) * 8 + j) * 64 + wib * 16 + (lane & 15)];
  }
  unsigned swv[4];
#pragma unroll
  for (int jj = 0; jj < 4; ++jj)
    swv[jj] = *(const unsigned*)(tab + (((unsigned)(base16 + wib * 4 + jj) << 6) + ch4));
#pragma unroll
  for (int jj = 0; jj < 4; ++jj) {
    int il = wib * 4 + jj;
    int i = base16 + il;
    int stl = sst[il] - span0;
    int c = scn[il];
    if (stl + c > EC) c = (EC > stl) ? (EC - stl) : 0;
    float di = dis[i] * FP8_SINV;
    floatx2 aLO = {0.f, 0.f}, aHI = {0.f, 0.f};
    GATHER_NODE(c, stl, aLO, aHI)
    float ax = aLO.x, ay = aLO.y, az = aHI.x, aw = aHI.y;
    ax += __shfl_xor(ax, 16, 64); ax += __shfl_xor(ax, 32, 64);
    ay += __shfl_xor(ay, 16, 64); ay += __shfl_xor(ay, 32, 64);
    az += __shfl_xor(az, 16, 64); az += __shfl_xor(az, 32, 64);
    aw += __shfl_xor(aw, 16, 64); aw += __shfl_xor(aw, 32, 64);
    floatx2 slo = __builtin_amdgcn_cvt_pk_f32_fp8(swv[jj], 0);
    floatx2 shi = __builtin_amdgcn_cvt_pk_f32_fp8(swv[jj], 1);
    if (es == 0) {
      half4v r;
      r[0] = (__fp16)fmaxf((ax + slo.x) * di + bv.x, 0.f);
      r[1] = (__fp16)fmaxf((ay + slo.y) * di + bv.y, 0.f);
      r[2] = (__fp16)fmaxf((az + shi.x) * di + bv.z, 0.f);
      r[3] = (__fp16)fmaxf((aw + shi.y) * di + bv.w, 0.f);
      *(half4v*)(g1s + il * 72 + ch * 4) = r;
    }
  }
  __syncthreads();
  int m = lane & 15;
  int q = lane >> 4;
  half8 a0 = *(const half8*)(g1s + m * 72 + q * 8);
  half8 a1 = *(const half8*)(g1s + m * 72 + 32 + q * 8);
  floatx4 acc = {0.f, 0.f, 0.f, 0.f};
  acc = __builtin_amdgcn_mfma_f32_16x16x32_f16(a0, b0, acc, 0, 0, 0);
  acc = __builtin_amdgcn_mfma_f32_16x16x32_f16(a1, b1, acc, 0, 0, 0);
  float sv[4];
#pragma unroll
  for (int r = 0; r < 4; ++r)
    sv[r] = acc[r] * dis[base16 + q * 4 + r] * FP8_SCALE;
  int u = __builtin_amdgcn_cvt_pk_fp8_f32(sv[0], sv[1], 0, 0);
  u = __builtin_amdgcn_cvt_pk_fp8_f32(sv[2], sv[3], u, 1);
#pragma unroll
  for (int r = 0; r < 4; ++r) {
    int node = base16 + q * 4 + r;
    xw2[(size_t)node * 64 + wib * 16 + m] = (unsigned char)(((unsigned)u) >> (8 * r));
  }
}

// ---------------- GCN aggregate layer-2 (fp8 table, staged span) + mean-pool
__global__ __launch_bounds__(256) void gcn_aggregate_pool(const unsigned char* __restrict__ tab,
    const int* __restrict__ ebuf, const int* __restrict__ estart,
    const int* __restrict__ ecnt, const float* __restrict__ dis,
    const float* __restrict__ bias, float* __restrict__ pool, int N) {
  __shared__ float4 red[4][16];
  __shared__ int sidx[EC + 16];
  __shared__ int sst[16], scn[16];
  int t = threadIdx.x;
  int base16 = blockIdx.x * 16;
  if (t < 16) {
    sst[t] = estart[base16 + t];
    scn[t] = ecnt[base16 + t];
  }
  __syncthreads();
  int span0 = sst[0];
  int total = sst[15] + scn[15] - span0;
  if (total > EC) total = EC;
  STAGE_SIDX()
  __syncthreads();
  int lane = t & 63;
  int es = lane >> 4;
  int ch = lane & 15;
  int wib = t >> 6;
  unsigned ch4 = (unsigned)ch * 4u;
  unsigned zoff = ((unsigned)ZROW << 6) + ch4;
  float4 bv = *(const float4*)(bias + ch * 4);
  unsigned swv[4];
#pragma unroll
  for (int jj = 0; jj < 4; ++jj)
    swv[jj] = *(const unsigned*)(tab + (((unsigned)(base16 + wib * 4 + jj) << 6) + ch4));
  float px = 0.f, py = 0.f, pz = 0.f, pw = 0.f;
#pragma unroll
  for (int jj = 0; jj < 4; ++jj) {
    int il = wib * 4 + jj;
    int i = base16 + il;
    int stl = sst[il] - span0;
    int c = scn[il];
    if (stl + c > EC) c = (EC > stl) ? (EC - stl) : 0;
    float di = dis[i] * FP8_SINV;
    floatx2 aLO = {0.f, 0.f}, aHI = {0.f, 0.f};
    GATHER_NODE(c, stl, aLO, aHI)
    float ax = aLO.x, ay = aLO.y, az = aHI.x, aw = aHI.y;
    ax += __shfl_xor(ax, 16, 64); ax += __shfl_xor(ax, 32, 64);
    ay += __shfl_xor(ay, 16, 64); ay += __shfl_xor(ay, 32, 64);
    az += __shfl_xor(az, 16, 64); az += __shfl_xor(az, 32, 64);
    aw += __shfl_xor(aw, 16, 64); aw += __shfl_xor(aw, 32, 64);
    floatx2 slo = __builtin_amdgcn_cvt_pk_f32_fp8(swv[jj], 0);
    floatx2 shi = __builtin_amdgcn_cvt_pk_f32_fp8(swv[jj], 1);
    px += fmaxf((ax + slo.x) * di + bv.x, 0.f);
    py += fmaxf((ay + slo.y) * di + bv.y, 0.f);
    pz += fmaxf((az + shi.x) * di + bv.z, 0.f);
    pw += fmaxf((aw + shi.y) * di + bv.w, 0.f);
  }
  if (es == 0) red[wib][ch] = make_float4(px, py, pz, pw);
  __syncthreads();
  if (threadIdx.x < 64) {
    int f = threadIdx.x;
    int c4 = f >> 2, j4 = f & 3;
    const float* r0 = (const float*)&red[0][c4];
    const float* r1 = (const float*)&red[1][c4];
    const float* r2 = (const float*)&red[2][c4];
    const float* r3 = (const float*)&red[3][c4];
    float sum = r0[j4] + r1[j4] + r2[j4] + r3[j4];
    int b = (blockIdx.x * 16) >> 11;
    atomicAdd(&pool[b * 64 + f], sum);
  }
}

// ---------------- classifier: out[b] = (pool[b]/2048) @ cls_w + cls_b
__global__ __launch_bounds__(64) void classify(const float* __restrict__ pool,
    const float* __restrict__ cw, const float* __restrict__ cb,
    float* __restrict__ out) {
  __shared__ float pl[64];
  int b = blockIdx.x;
  int t = threadIdx.x;
  pl[t] = pool[b * 64 + t] * (1.0f / (float)T2);
  __syncthreads();
  if (t < NOUT) {
    float a = cb[t];
#pragma unroll
    for (int k = 0; k < 64; ++k) a += pl[k] * cw[k * NOUT + t];
    out[b * NOUT + t] = a;
  }
}

extern "C" void kernel_launch(void* const* d_in, const int* in_sizes, int n_in,
                              void* d_out, int out_size, void* d_ws, size_t ws_size,
                              hipStream_t stream) {
  const float* x    = (const float*)d_in[0];
  const int*   ei   = (const int*)d_in[1];
  const float* c1w  = (const float*)d_in[2];
  const float* c1b  = (const float*)d_in[3];
  const float* c2w  = (const float*)d_in[4];
  const float* c2b  = (const float*)d_in[5];
  const float* g1w  = (const float*)d_in[6];
  const float* g1b  = (const float*)d_in[7];
  const float* g2w  = (const float*)d_in[8];
  const float* g2b  = (const float*)d_in[9];
  const float* cw   = (const float*)d_in[10];
  const float* cb   = (const float*)d_in[11];
  float* out = (float*)d_out;
  int E = in_sizes[1] / 2;
  const int N = N_NODES;

  // workspace layout (bytes); xw/xw2 are fp8 tables with N+1 rows of 64 B.
  // deg_g lives in the slack between xw's end (28,856,384) and xw2.
  char* ws = (char*)d_ws;
  int*    gpairs = (int*)(ws);                     //  9,437,184 (packed 4B)
  int*    ebuf   = (int*)(ws + 9437184);           //  9,437,184
  int*    rcnt   = (int*)(ws + 18874368);          //      4,096
  int*    estart = (int*)(ws + 18878464);          //    524,288
  int*    ecnt   = (int*)(ws + 19402752);          //    524,288
  float*  dis    = (float*)(ws + 19927040);        //    524,288
  float*  pool   = (float*)(ws + 20451328);        //     16,384
  unsigned char* xw  = (unsigned char*)(ws + 20467712);  // 8,388,672 fp8
  int*    deg_g  = (int*)(ws + 28856384);          //    524,288
  unsigned char* xw2 = (unsigned char*)(ws + 37245184);  // 8,388,672 fp8
  __fp16* h1     = (__fp16*)(ws + 54022656);       //  8,388,608 ([b][T1][16] fp16)

  hipMemsetAsync(rcnt, 0, NCB * sizeof(int), stream);
  hipMemsetAsync(deg_g, 0, N_NODES * sizeof(int), stream);

  // fused: conv1 (even blocks) || edge partition + degrees (odd blocks)
  conv1_partition<<<dim3(BATCH * 16 * 2), dim3(256), 0, stream>>>(
      x, c1w, c1b, h1, ei, E, rcnt, gpairs, deg_g, pool, xw, xw2);

  // fused: build_csr (bid%3==0) || conv2+gemm1 (other blocks, dis from deg_g)
  csr_conv2<<<dim3(NCB * 3), dim3(512), 0, stream>>>(
      gpairs, rcnt, ebuf, estart, ecnt, dis, h1, c2w, c2b, g1w, deg_g, xw);

  agg1_gemm2<<<dim3(N / 16), dim3(256), 0, stream>>>(xw, ebuf, estart, ecnt, dis, g1b, g2w, xw2, N);
  gcn_aggregate_pool<<<dim3(N / 16), dim3(256), 0, stream>>>(xw2, ebuf, estart, ecnt, dis, g2b, pool, N);

  classify<<<dim3(BATCH), dim3(64), 0, stream>>>(pool, cw, cb, out);
}

// Round 14
// 245.499 us; speedup vs baseline: 1.3169x; 1.3169x over previous
//
#include <hip/hip_runtime.h>
#include <hip/hip_bf16.h>
#include <hip/hip_fp16.h>

// Problem constants
#define BATCH 64
#define C_IN 16
#define T0 8192
#define T1 4096   // after pool1
#define T2 2048   // after pool2 (nodes per batch)
#define N_NODES (BATCH * T2)   // 131072
#define HID 64
#define NOUT 10

// Coarse-bucket edge partition parameters
#define NCB 256
#define CB_SHIFT 9
#define CB_TGT 512
#define RCAP 9216
#define PC_EDGES 2048
#define PC_CAP 28

// packed edge record: bits[0:17) = source r, bits[17:26) = local col
#define PK_RMASK 0x1FFFF

// per-block staged edge-span capacity
#define EC 1024

// zero-row index (tables have N_NODES+1 rows; row N_NODES is all zeros)
#define ZROW N_NODES

// transposed conv-input LDS tile: row = position, 16 ci halves + pad.
// ROWW=24 halves (48B = 12 words): b128 reads at pos*12 words tile all 32
// banks (stride-12 start-bank cycle {0,12,24,4,16,28,8,20} -> 2-way = free).
#define ROWW 24

// fp8 gather tables: rows scaled by S on store, /S folded into dis at agg.
#define FP8_SCALE 256.0f
#define FP8_SINV  (1.0f / 256.0f)

typedef __fp16 half8 __attribute__((ext_vector_type(8)));
typedef __fp16 half4v __attribute__((ext_vector_type(4)));
typedef float floatx4 __attribute__((ext_vector_type(4)));
typedef float floatx2 __attribute__((ext_vector_type(2)));

// ---------------- FUSED conv1 + partition (r12 state — session best 246.7us).
// r13 lesson: do NOT add global-degree atomics here (2M random atomics
// dirtied ~65MB of write traffic and took this kernel 46->115us).
__global__ __launch_bounds__(256) void conv1_partition(
    const float* __restrict__ x, const float* __restrict__ w,
    const float* __restrict__ bias, __fp16* __restrict__ h1,
    const int* __restrict__ ei, int E,
    int* __restrict__ rcnt, int* __restrict__ gpairs,
    float* __restrict__ pool, unsigned char* __restrict__ xw,
    unsigned char* __restrict__ xw2) {
  __shared__ int smem_i[NCB + NCB * PC_CAP];   // 29,696 B union
  if ((blockIdx.x & 1) == 0) {
    // ======== conv1 path (MFMA im2col GEMM, K=80 pad 96, N=16co)
    __fp16* xs = (__fp16*)smem_i;              // 528*24*2 = 25,344 B
    int bid = blockIdx.x >> 1;
    int b = bid >> 4;
    int tp0 = (bid & 15) * 256;
    if (bid == 0) {
      for (int k = threadIdx.x; k < BATCH * HID; k += 256) pool[k] = 0.f;
      if (threadIdx.x < 16) {
        ((unsigned*)(xw + (size_t)ZROW * 64))[threadIdx.x] = 0u;
        ((unsigned*)(xw2 + (size_t)ZROW * 64))[threadIdx.x] = 0u;
      }
    }
    int t_base = 2 * tp0 - 8;
    const float* xb = x + (size_t)b * C_IN * T0;
    // contiguous + batched staging: group g (16 threads) owns row ci=g;
    // lane covers chunks c4 = l16 + 16k, k=0..8 (k=8 partial).
    {
      int ci = threadIdx.x >> 4;
      int l16 = threadIdx.x & 15;
      const float* xrow = xb + ci * T0;
      float4 va[4];
#pragma unroll
      for (int k = 0; k < 4; ++k) {
        int c4 = l16 + k * 16;
        int gt = t_base + c4 * 4;
        va[k] = make_float4(0.f, 0.f, 0.f, 0.f);
        if (gt >= 0 && gt + 4 <= T0) va[k] = *(const float4*)(xrow + gt);
      }
#pragma unroll
      for (int k = 0; k < 4; ++k) {
        int c4 = l16 + k * 16;
        __fp16* d = xs + (c4 * 4) * ROWW + ci;
        d[0] = (__fp16)va[k].x;
        d[ROWW] = (__fp16)va[k].y;
        d[2 * ROWW] = (__fp16)va[k].z;
        d[3 * ROWW] = (__fp16)va[k].w;
      }
      float4 vb[5];
      int okb[5];
#pragma unroll
      for (int k = 0; k < 5; ++k) {
        int c4 = l16 + (4 + k) * 16;
        okb[k] = (c4 < 132);
        int gt = t_base + c4 * 4;
        vb[k] = make_float4(0.f, 0.f, 0.f, 0.f);
        if (okb[k] && gt >= 0 && gt + 4 <= T0) vb[k] = *(const float4*)(xrow + gt);
      }
#pragma unroll
      for (int k = 0; k < 5; ++k) {
        if (okb[k]) {
          int c4 = l16 + (4 + k) * 16;
          __fp16* d = xs + (c4 * 4) * ROWW + ci;
          d[0] = (__fp16)vb[k].x;
          d[ROWW] = (__fp16)vb[k].y;
          d[2 * ROWW] = (__fp16)vb[k].z;
          d[3 * ROWW] = (__fp16)vb[k].w;
        }
      }
    }
    int ln = threadIdx.x & 15;
    int q = (threadIdx.x & 63) >> 4;
    int wib = threadIdx.x >> 6;
    half8 wb[3];
#pragma unroll
    for (int ks = 0; ks < 3; ++ks) {
      int kk = ks * 2 + (q >> 1);
#pragma unroll
      for (int j = 0; j < 8; ++j) {
        int ci = (q & 1) * 8 + j;
        float wv = (kk < 5) ? w[(ln * 16 + ci) * 5 + kk] : 0.f;
        wb[ks][j] = (__fp16)wv;
      }
    }
    float bv = bias[ln];
    __syncthreads();
    int qh = q >> 1, qo = (q & 1) * 8;
#pragma unroll 2
    for (int mtl = 0; mtl < 8; ++mtl) {
      int mt = wib * 8 + mtl;
      int posb = mt * 16 + ln + qh + 6;
      half8 a0 = *(const half8*)(xs + posb * ROWW + qo);
      half8 a1 = *(const half8*)(xs + (posb + 2) * ROWW + qo);
      half8 a2 = *(const half8*)(xs + (posb + 4) * ROWW + qo);
      floatx4 c0 = {0.f, 0.f, 0.f, 0.f};
      c0 = __builtin_amdgcn_mfma_f32_16x16x32_f16(a0, wb[0], c0, 0, 0, 0);
      c0 = __builtin_amdgcn_mfma_f32_16x16x32_f16(a1, wb[1], c0, 0, 0, 0);
      c0 = __builtin_amdgcn_mfma_f32_16x16x32_f16(a2, wb[2], c0, 0, 0, 0);
      int tp = tp0 + mt * 8 + q * 2;
      size_t o = ((size_t)b * T1 + tp) * 16 + ln;
      h1[o] = (__fp16)fmaxf(fmaxf(c0[0], c0[1]) + bv, 0.f);
      h1[o + 16] = (__fp16)fmaxf(fmaxf(c0[2], c0[3]) + bv, 0.f);
    }
  } else {
    // ======== partition path: preload 8 edges (one wait), then 8
    // independent atomic-slot chains.
    int* lcnt = smem_i;
    int* lpk = smem_i + NCB;
    int pid = blockIdx.x >> 1;
    if (threadIdx.x < NCB) lcnt[threadIdx.x] = 0;
    __syncthreads();
    int e0 = pid * PC_EDGES;
    int rr[8], cc[8];
#pragma unroll
    for (int j = 0; j < 8; ++j) {
      int e = e0 + j * 256 + threadIdx.x;
      rr[j] = (e < E) ? ei[e] : 0;
      cc[j] = (e < E) ? ei[E + e] : -1;
    }
#pragma unroll
    for (int j = 0; j < 8; ++j) {
      if (cc[j] >= 0) {
        int cb = cc[j] >> CB_SHIFT;
        int pk = rr[j] | ((cc[j] & (CB_TGT - 1)) << 17);
        int slot = atomicAdd(&lcnt[cb], 1);
        if (slot < PC_CAP) {
          lpk[cb * PC_CAP + slot] = pk;
        } else {
          int pos = atomicAdd(&rcnt[cb], 1);
          if (pos < RCAP) gpairs[(size_t)cb * RCAP + pos] = pk;
        }
      }
    }
    __syncthreads();
    int t = threadIdx.x;
    if (t < NCB) {
      int n = lcnt[t];
      if (n > PC_CAP) n = PC_CAP;
      if (n > 0) {
        int base = atomicAdd(&rcnt[t], n);
        int* dst = gpairs + (size_t)t * RCAP;
        for (int k = 0; k < n; ++k) {
          int p = base + k;
          if (p < RCAP) dst[p] = lpk[t * PC_CAP + k];
        }
      }
    }
  }
}

// ---------------- conv2 + gemm1 fused (MFMA conv): h1 [b][T1][16] -> conv GEMM
// (K=80 pad 96, N=32co) -> relu/pool -> fs LDS -> MFMA @W1 -> xw (fp8, scaled)
__global__ __launch_bounds__(256) void conv2_gemm1(const __fp16* __restrict__ h1,
    const float* __restrict__ w, const float* __restrict__ bias,
    const float* __restrict__ W1, const float* __restrict__ dis,
    unsigned char* __restrict__ xw) {
  __shared__ __fp16 xs[520 * ROWW];
  __shared__ __fp16 fs[256 * 40];
  int b = blockIdx.x >> 3;
  int tp0 = (blockIdx.x & 7) * 256;
  int t_base = 2 * tp0 - 2;
  // batched register staging: 1040 chunks = 4*256 + 16; 5 preloads, 1 wait.
  {
    half8 v[5];
    int row_[5], hf_[5], ok_[5];
#pragma unroll
    for (int k = 0; k < 5; ++k) {
      int idx = threadIdx.x + k * 256;
      ok_[k] = (idx < 520 * 2);
      int row = idx >> 1, hf = idx & 1;
      int gt = t_base + row;
      half8 z;
#pragma unroll
      for (int j = 0; j < 8; ++j) z[j] = (__fp16)0.f;
      v[k] = z;
      if (ok_[k] && gt >= 0 && gt < T1)
        v[k] = *(const half8*)(h1 + ((size_t)b * T1 + gt) * 16 + hf * 8);
      row_[k] = row; hf_[k] = hf;
    }
#pragma unroll
    for (int k = 0; k < 5; ++k)
      if (ok_[k]) *(half8*)(xs + row_[k] * ROWW + hf_[k] * 8) = v[k];
  }
  int ln = threadIdx.x & 15;
  int q = (threadIdx.x & 63) >> 4;
  int wib = threadIdx.x >> 6;
  half8 wb[2][3];
#pragma unroll
  for (int nt = 0; nt < 2; ++nt)
#pragma unroll
    for (int ks = 0; ks < 3; ++ks) {
      int kk = ks * 2 + (q >> 1);
#pragma unroll
      for (int j = 0; j < 8; ++j) {
        int ci = (q & 1) * 8 + j;
        float wv = (kk < 5) ? w[((nt * 16 + ln) * 16 + ci) * 5 + kk] : 0.f;
        wb[nt][ks][j] = (__fp16)wv;
      }
    }
  float b20 = bias[ln];
  float b21 = bias[16 + ln];
  __syncthreads();
  int qh = q >> 1, qo = (q & 1) * 8;
#pragma unroll 2
  for (int mtl = 0; mtl < 8; ++mtl) {
    int mt = wib * 8 + mtl;
    int posb = mt * 16 + ln + qh;
    half8 a0 = *(const half8*)(xs + posb * ROWW + qo);
    half8 a1 = *(const half8*)(xs + (posb + 2) * ROWW + qo);
    half8 a2 = *(const half8*)(xs + (posb + 4) * ROWW + qo);
    floatx4 c0 = {0.f, 0.f, 0.f, 0.f};
    floatx4 c1 = {0.f, 0.f, 0.f, 0.f};
    c0 = __builtin_amdgcn_mfma_f32_16x16x32_f16(a0, wb[0][0], c0, 0, 0, 0);
    c0 = __builtin_amdgcn_mfma_f32_16x16x32_f16(a1, wb[0][1], c0, 0, 0, 0);
    c0 = __builtin_amdgcn_mfma_f32_16x16x32_f16(a2, wb[0][2], c0, 0, 0, 0);
    c1 = __builtin_amdgcn_mfma_f32_16x16x32_f16(a0, wb[1][0], c1, 0, 0, 0);
    c1 = __builtin_amdgcn_mfma_f32_16x16x32_f16(a1, wb[1][1], c1, 0, 0, 0);
    c1 = __builtin_amdgcn_mfma_f32_16x16x32_f16(a2, wb[1][2], c1, 0, 0, 0);
    int node = wib * 64 + mtl * 8 + q * 2;
    fs[node * 40 + ln] = (__fp16)fmaxf(fmaxf(c0[0], c0[1]) + b20, 0.f);
    fs[(node + 1) * 40 + ln] = (__fp16)fmaxf(fmaxf(c0[2], c0[3]) + b20, 0.f);
    fs[node * 40 + 16 + ln] = (__fp16)fmaxf(fmaxf(c1[0], c1[1]) + b21, 0.f);
    fs[(node + 1) * 40 + 16 + ln] = (__fp16)fmaxf(fmaxf(c1[2], c1[3]) + b21, 0.f);
  }
  half8 bf[4];
#pragma unroll
  for (int t = 0; t < 4; ++t)
#pragma unroll
    for (int j = 0; j < 8; ++j)
      bf[t][j] = (__fp16)W1[(q * 8 + j) * 64 + ln * 4 + t];
  int gnode0 = b * T2 + tp0;
#pragma unroll
  for (int tt = 0; tt < 4; ++tt) {
    int lbase = (wib * 4 + tt) * 16;
    half8 a = *(const half8*)(fs + (lbase + ln) * 40 + q * 8);
    float d[4];
#pragma unroll
    for (int r = 0; r < 4; ++r) d[r] = dis[gnode0 + lbase + q * 4 + r] * FP8_SCALE;
    floatx4 acc[4];
#pragma unroll
    for (int t = 0; t < 4; ++t) {
      floatx4 z = {0.f, 0.f, 0.f, 0.f};
      acc[t] = __builtin_amdgcn_mfma_f32_16x16x32_f16(a, bf[t], z, 0, 0, 0);
    }
#pragma unroll
    for (int r = 0; r < 4; ++r) {
      int u = __builtin_amdgcn_cvt_pk_fp8_f32(acc[0][r] * d[r], acc[1][r] * d[r], 0, 0);
      u = __builtin_amdgcn_cvt_pk_fp8_f32(acc[2][r] * d[r], acc[3][r] * d[r], u, 1);
      *(unsigned*)(xw + (size_t)(gnode0 + lbase + q * 4 + r) * 64 + ln * 4) = (unsigned)u;
    }
  }
}

// ---------------- pass D: per coarse bucket, exact-degree CSR via wave-scans
// both scatter loops 4-deep batched (preload independent, then consume).
__global__ __launch_bounds__(512) void build_csr(const int* __restrict__ gpairs,
    const int* __restrict__ rcnt, int* __restrict__ ebuf,
    int* __restrict__ estart, int* __restrict__ ecnt, float* __restrict__ dis) {
  __shared__ int deg[CB_TGT];
  __shared__ int cur[CB_TGT];
  __shared__ int sc[CB_TGT];
  __shared__ int wsum[8];
  int b = blockIdx.x;
  int t = threadIdx.x;
  deg[t] = 0;
  cur[t] = 0;
  __syncthreads();
  int m = rcnt[b];
  if (m > RCAP) m = RCAP;
  const int* reg = gpairs + (size_t)b * RCAP;
  for (int k0 = 0; k0 < m; k0 += 2048) {
    int p[4], have[4];
#pragma unroll
    for (int u = 0; u < 4; ++u) {
      int k = k0 + u * 512 + t;
      have[u] = (k < m);
      p[u] = have[u] ? reg[k] : 0;
    }
#pragma unroll
    for (int u = 0; u < 4; ++u)
      if (have[u]) atomicAdd(&deg[(p[u] >> 17) & (CB_TGT - 1)], 1);
  }
  __syncthreads();
  int d = deg[t];
  int lane = t & 63;
  int wv = t >> 6;
  int sum = d;
#pragma unroll
  for (int off = 1; off < 64; off <<= 1) {
    int v = __shfl_up(sum, off, 64);
    if (lane >= off) sum += v;
  }
  if (lane == 63) wsum[wv] = sum;
  __syncthreads();
  int prefix = 0;
#pragma unroll
  for (int i = 0; i < 8; ++i) prefix += (i < wv) ? wsum[i] : 0;
  int excl = prefix + sum - d;
  int gi = (b << CB_SHIFT) + t;
  int base = b * RCAP;
  estart[gi] = base + excl;
  ecnt[gi] = d;
  dis[gi] = rsqrtf((float)d + 1.0f);
  sc[t] = excl;
  __syncthreads();
  for (int k0 = 0; k0 < m; k0 += 2048) {
    int p[4], have[4];
#pragma unroll
    for (int u = 0; u < 4; ++u) {
      int k = k0 + u * 512 + t;
      have[u] = (k < m);
      p[u] = have[u] ? reg[k] : 0;
    }
#pragma unroll
    for (int u = 0; u < 4; ++u) {
      if (have[u]) {
        int lc = (p[u] >> 17) & (CB_TGT - 1);
        int off = atomicAdd(&cur[lc], 1);
        ebuf[base + sc[lc] + off] = p[u] & PK_RMASK;
      }
    }
  }
}

// ======== gather (fp8 rows, 64 B = 1 cache line), PING-PONG double-buffered
// 16-edge windows (r6 structure — best verified). es = lane>>4, ch = lane&15.
#define LOADW(dst_, b0_)                                                        \
  _Pragma("unroll")                                                             \
  for (int j = 0; j < 4; ++j) {                                                 \
    unsigned r = (unsigned)sidx[(b0_) + j * 4];                                 \
    dst_[j] = *(const unsigned*)(tab + ((r << 6) + ch4));                       \
  }
#define LOADWT(dst_, stl_, s0_, c_)                                             \
  _Pragma("unroll")                                                             \
  for (int j = 0; j < 4; ++j) {                                                 \
    int k = (s0_) + j * 4 + es;                                                 \
    unsigned r = (unsigned)sidx[(stl_) + k];                                    \
    unsigned off = (k < (c_)) ? ((r << 6) + ch4) : zoff;                        \
    dst_[j] = *(const unsigned*)(tab + off);                                    \
  }
#define CONSW(src_, ALO, AHI)                                                   \
  _Pragma("unroll")                                                             \
  for (int j = 0; j < 4; ++j) {                                                 \
    ALO += __builtin_amdgcn_cvt_pk_f32_fp8(src_[j], 0);                         \
    AHI += __builtin_amdgcn_cvt_pk_f32_fp8(src_[j], 1);                         \
  }
#define GATHER_NODE(c_, stl_, ALO, AHI)                                         \
  {                                                                             \
    int sb_ = (stl_) + es;                                                      \
    int nt_ = ((c_) + 15) >> 4;                                                 \
    int nf_ = (c_) >> 4;                                                        \
    unsigned wa_[4], wb_[4];                                                    \
    if (nt_ > 0) {                                                              \
      if (nf_ > 0) { LOADW(wa_, sb_) } else { LOADWT(wa_, stl_, 0, c_) }        \
    }                                                                           \
    for (int w_ = 0; w_ < nt_; ++w_) {                                          \
      int n_ = w_ + 1;                                                          \
      if (n_ < nt_) {                                                           \
        if (w_ & 1) {                                                           \
          if (n_ < nf_) { LOADW(wa_, sb_ + (n_ << 4)) }                         \
          else { LOADWT(wa_, stl_, n_ << 4, c_) }                               \
        } else {                                                                \
          if (n_ < nf_) { LOADW(wb_, sb_ + (n_ << 4)) }                         \
          else { LOADWT(wb_, stl_, n_ << 4, c_) }                               \
        }                                                                       \
      }                                                                         \
      if (w_ & 1) { CONSW(wb_, ALO, AHI) } else { CONSW(wa_, ALO, AHI) }        \
    }                                                                           \
  }

// ======== batched sidx staging: EC = 1024 = 4*256 -> 4 preloads, 1 wait
#define STAGE_SIDX()                                                            \
  {                                                                             \
    int v0 = 0, v1 = 0, v2 = 0, v3 = 0;                                         \
    if (t < total) v0 = ebuf[span0 + t];                                        \
    if (t + 256 < total) v1 = ebuf[span0 + t + 256];                            \
    if (t + 512 < total) v2 = ebuf[span0 + t + 512];                            \
    if (t + 768 < total) v3 = ebuf[span0 + t + 768];                            \
    if (t < total) sidx[t] = v0;                                                \
    if (t + 256 < total) sidx[t + 256] = v1;                                    \
    if (t + 512 < total) sidx[t + 512] = v2;                                    \
    if (t + 768 < total) sidx[t + 768] = v3;                                    \
  }

// ---------------- agg1 + gemm2 fused (fp8 table, staged edge span)
__global__ __launch_bounds__(256) void agg1_gemm2(const unsigned char* __restrict__ tab,
    const int* __restrict__ ebuf, const int* __restrict__ estart,
    const int* __restrict__ ecnt, const float* __restrict__ dis,
    const float* __restrict__ bias, const float* __restrict__ W2,
    unsigned char* __restrict__ xw2, int N) {
  __shared__ __fp16 g1s[16 * 72];
  __shared__ int sidx[EC + 16];   // +16: tail window may over-read in-bounds
  __shared__ int sst[16], scn[16];
  int t = threadIdx.x;
  int base16 = blockIdx.x * 16;
  if (t < 16) {
    sst[t] = estart[base16 + t];
    scn[t] = ecnt[base16 + t];
  }
  __syncthreads();
  int span0 = sst[0];
  int total = sst[15] + scn[15] - span0;
  if (total > EC) total = EC;
  STAGE_SIDX()
  __syncthreads();
  int lane = t & 63;
  int es = lane >> 4;
  int ch = lane & 15;
  int wib = t >> 6;
  unsigned ch4 = (unsigned)ch * 4u;
  unsigned zoff = ((unsigned)ZROW << 6) + ch4;
  float4 bv = *(const float4*)(bias + ch * 4);
  // gemm2 W2 fragments hoisted BEFORE the gather (r8: −10% on this kernel)
  half8 b0, b1;
#pragma unroll
  for (int j = 0; j < 8; ++j) {
    b0[j] = (__fp16)W2[((lane >> 4) * 8 + j) * 64 + wib * 16 + (lane & 15)];
    b1[j] = (__fp16)W2[(32 + (lane >> 4) * 8 + j) * 64 + wib * 16 + (lane & 15)];
  }
  unsigned swv[4];
#pragma unroll
  for (int jj = 0; jj < 4; ++jj)
    swv[jj] = *(const unsigned*)(tab + (((unsigned)(base16 + wib * 4 + jj) << 6) + ch4));
#pragma unroll
  for (int jj = 0; jj < 4; ++jj) {
    int il = wib * 4 + jj;
    int i = base16 + il;
    int stl = sst[il] - span0;
    int c = scn[il];
    if (stl + c > EC) c = (EC > stl) ? (EC - stl) : 0;
    float di = dis[i] * FP8_SINV;
    floatx2 aLO = {0.f, 0.f}, aHI = {0.f, 0.f};
    GATHER_NODE(c, stl, aLO, aHI)
    float ax = aLO.x, ay = aLO.y, az = aHI.x, aw = aHI.y;
    ax += __shfl_xor(ax, 16, 64); ax += __shfl_xor(ax, 32, 64);
    ay += __shfl_xor(ay, 16, 64); ay += __shfl_xor(ay, 32, 64);
    az += __shfl_xor(az, 16, 64); az += __shfl_xor(az, 32, 64);
    aw += __shfl_xor(aw, 16, 64); aw += __shfl_xor(aw, 32, 64);
    floatx2 slo = __builtin_amdgcn_cvt_pk_f32_fp8(swv[jj], 0);
    floatx2 shi = __builtin_amdgcn_cvt_pk_f32_fp8(swv[jj], 1);
    if (es == 0) {
      half4v r;
      r[0] = (__fp16)fmaxf((ax + slo.x) * di + bv.x, 0.f);
      r[1] = (__fp16)fmaxf((ay + slo.y) * di + bv.y, 0.f);
      r[2] = (__fp16)fmaxf((az + shi.x) * di + bv.z, 0.f);
      r[3] = (__fp16)fmaxf((aw + shi.y) * di + bv.w, 0.f);
      *(half4v*)(g1s + il * 72 + ch * 4) = r;
    }
  }
  __syncthreads();
  int m = lane & 15;
  int q = lane >> 4;
  half8 a0 = *(const half8*)(g1s + m * 72 + q * 8);
  half8 a1 = *(const half8*)(g1s + m * 72 + 32 + q * 8);
  floatx4 acc = {0.f, 0.f, 0.f, 0.f};
  acc = __builtin_amdgcn_mfma_f32_16x16x32_f16(a0, b0, acc, 0, 0, 0);
  acc = __builtin_amdgcn_mfma_f32_16x16x32_f16(a1, b1, acc, 0, 0, 0);
  float sv[4];
#pragma unroll
  for (int r = 0; r < 4; ++r)
    sv[r] = acc[r] * dis[base16 + q * 4 + r] * FP8_SCALE;
  int u = __builtin_amdgcn_cvt_pk_fp8_f32(sv[0], sv[1], 0, 0);
  u = __builtin_amdgcn_cvt_pk_fp8_f32(sv[2], sv[3], u, 1);
#pragma unroll
  for (int r = 0; r < 4; ++r) {
    int node = base16 + q * 4 + r;
    xw2[(size_t)node * 64 + wib * 16 + m] = (unsigned char)(((unsigned)u) >> (8 * r));
  }
}

// ---------------- GCN aggregate layer-2 (fp8 table, staged span) + mean-pool
__global__ __launch_bounds__(256) void gcn_aggregate_pool(const unsigned char* __restrict__ tab,
    const int* __restrict__ ebuf, const int* __restrict__ estart,
    const int* __restrict__ ecnt, const float* __restrict__ dis,
    const float* __restrict__ bias, float* __restrict__ pool, int N) {
  __shared__ float4 red[4][16];
  __shared__ int sidx[EC + 16];
  __shared__ int sst[16], scn[16];
  int t = threadIdx.x;
  int base16 = blockIdx.x * 16;
  if (t < 16) {
    sst[t] = estart[base16 + t];
    scn[t] = ecnt[base16 + t];
  }
  __syncthreads();
  int span0 = sst[0];
  int total = sst[15] + scn[15] - span0;
  if (total > EC) total = EC;
  STAGE_SIDX()
  __syncthreads();
  int lane = t & 63;
  int es = lane >> 4;
  int ch = lane & 15;
  int wib = t >> 6;
  unsigned ch4 = (unsigned)ch * 4u;
  unsigned zoff = ((unsigned)ZROW << 6) + ch4;
  float4 bv = *(const float4*)(bias + ch * 4);
  unsigned swv[4];
#pragma unroll
  for (int jj = 0; jj < 4; ++jj)
    swv[jj] = *(const unsigned*)(tab + (((unsigned)(base16 + wib * 4 + jj) << 6) + ch4));
  float px = 0.f, py = 0.f, pz = 0.f, pw = 0.f;
#pragma unroll
  for (int jj = 0; jj < 4; ++jj) {
    int il = wib * 4 + jj;
    int i = base16 + il;
    int stl = sst[il] - span0;
    int c = scn[il];
    if (stl + c > EC) c = (EC > stl) ? (EC - stl) : 0;
    float di = dis[i] * FP8_SINV;
    floatx2 aLO = {0.f, 0.f}, aHI = {0.f, 0.f};
    GATHER_NODE(c, stl, aLO, aHI)
    float ax = aLO.x, ay = aLO.y, az = aHI.x, aw = aHI.y;
    ax += __shfl_xor(ax, 16, 64); ax += __shfl_xor(ax, 32, 64);
    ay += __shfl_xor(ay, 16, 64); ay += __shfl_xor(ay, 32, 64);
    az += __shfl_xor(az, 16, 64); az += __shfl_xor(az, 32, 64);
    aw += __shfl_xor(aw, 16, 64); aw += __shfl_xor(aw, 32, 64);
    floatx2 slo = __builtin_amdgcn_cvt_pk_f32_fp8(swv[jj], 0);
    floatx2 shi = __builtin_amdgcn_cvt_pk_f32_fp8(swv[jj], 1);
    px += fmaxf((ax + slo.x) * di + bv.x, 0.f);
    py += fmaxf((ay + slo.y) * di + bv.y, 0.f);
    pz += fmaxf((az + shi.x) * di + bv.z, 0.f);
    pw += fmaxf((aw + shi.y) * di + bv.w, 0.f);
  }
  if (es == 0) red[wib][ch] = make_float4(px, py, pz, pw);
  __syncthreads();
  if (threadIdx.x < 64) {
    int f = threadIdx.x;
    int c4 = f >> 2, j4 = f & 3;
    const float* r0 = (const float*)&red[0][c4];
    const float* r1 = (const float*)&red[1][c4];
    const float* r2 = (const float*)&red[2][c4];
    const float* r3 = (const float*)&red[3][c4];
    float sum = r0[j4] + r1[j4] + r2[j4] + r3[j4];
    int b = (blockIdx.x * 16) >> 11;
    atomicAdd(&pool[b * 64 + f], sum);
  }
}

// ---------------- classifier: out[b] = (pool[b]/2048) @ cls_w + cls_b
__global__ __launch_bounds__(64) void classify(const float* __restrict__ pool,
    const float* __restrict__ cw, const float* __restrict__ cb,
    float* __restrict__ out) {
  __shared__ float pl[64];
  int b = blockIdx.x;
  int t = threadIdx.x;
  pl[t] = pool[b * 64 + t] * (1.0f / (float)T2);
  __syncthreads();
  if (t < NOUT) {
    float a = cb[t];
#pragma unroll
    for (int k = 0; k < 64; ++k) a += pl[k] * cw[k * NOUT + t];
    out[b * NOUT + t] = a;
  }
}

extern "C" void kernel_launch(void* const* d_in, const int* in_sizes, int n_in,
                              void* d_out, int out_size, void* d_ws, size_t ws_size,
                              hipStream_t stream) {
  const float* x    = (const float*)d_in[0];
  const int*   ei   = (const int*)d_in[1];
  const float* c1w  = (const float*)d_in[2];
  const float* c1b  = (const float*)d_in[3];
  const float* c2w  = (const float*)d_in[4];
  const float* c2b  = (const float*)d_in[5];
  const float* g1w  = (const float*)d_in[6];
  const float* g1b  = (const float*)d_in[7];
  const float* g2w  = (const float*)d_in[8];
  const float* g2b  = (const float*)d_in[9];
  const float* cw   = (const float*)d_in[10];
  const float* cb   = (const float*)d_in[11];
  float* out = (float*)d_out;
  int E = in_sizes[1] / 2;
  const int N = N_NODES;

  // workspace layout (bytes); xw/xw2 are fp8 tables with N+1 rows of 64 B
  char* ws = (char*)d_ws;
  int*    gpairs = (int*)(ws);                     //  9,437,184 (packed 4B)
  int*    ebuf   = (int*)(ws + 9437184);           //  9,437,184
  int*    rcnt   = (int*)(ws + 18874368);          //      4,096
  int*    estart = (int*)(ws + 18878464);          //    524,288
  int*    ecnt   = (int*)(ws + 19402752);          //    524,288
  float*  dis    = (float*)(ws + 19927040);        //    524,288
  float*  pool   = (float*)(ws + 20451328);        //     16,384
  unsigned char* xw  = (unsigned char*)(ws + 20467712);  // 8,388,672 fp8
  unsigned char* xw2 = (unsigned char*)(ws + 37245184);  // 8,388,672 fp8
  __fp16* h1     = (__fp16*)(ws + 54022656);       //  8,388,608 ([b][T1][16] fp16)

  // only rcnt's memset must precede the fused kernel (partition atomics);
  // pool/zero-row clears are folded into conv1_partition block 0.
  hipMemsetAsync(rcnt, 0, NCB * sizeof(int), stream);

  // fused: conv1 (even blocks) || edge partition (odd blocks)
  conv1_partition<<<dim3(BATCH * 16 * 2), dim3(256), 0, stream>>>(
      x, c1w, c1b, h1, ei, E, rcnt, gpairs, pool, xw, xw2);

  build_csr<<<dim3(NCB), dim3(512), 0, stream>>>(gpairs, rcnt, ebuf, estart, ecnt, dis);

  conv2_gemm1<<<dim3(BATCH * 8), dim3(256), 0, stream>>>(h1, c2w, c2b, g1w, dis, xw);
  agg1_gemm2<<<dim3(N / 16), dim3(256), 0, stream>>>(xw, ebuf, estart, ecnt, dis, g1b, g2w, xw2, N);
  gcn_aggregate_pool<<<dim3(N / 16), dim3(256), 0, stream>>>(xw2, ebuf, estart, ecnt, dis, g2b, pool, N);

  classify<<<dim3(BATCH), dim3(64), 0, stream>>>(pool, cw, cb, out);
}